// Round 8
// baseline (440.182 us; speedup 1.0000x reference)
//
#include <hip/hip_runtime.h>

constexpr int NN = 100000;   // nodes
constexpr int NE = 1600000;  // edges
constexpr int NG = 5000;     // graphs
constexpr int BKT = 64;      // dst-nodes per bucket
constexpr int NBKT = (NN + BKT - 1) / BKT;   // 1563
constexpr int NB = 128;      // hist/scatter blocks
constexpr int CHUNK = NE / NB;               // 12500 exact

typedef float v2f __attribute__((ext_vector_type(2)));

// ---- workspace layout (4B words) ----
constexpr size_t OFF_G  = 0;                            // g      [NG*10]
constexpr size_t OFF_BH = 50048;                        // bh     [NB][NBKT]
constexpr size_t OFF_ST = OFF_BH + (size_t)NB * NBKT;   // starts [NBKT+1]
constexpr size_t OFF_PM = OFF_ST + NBKT + 1;            // perm OR inv [NE]
constexpr size_t OFF_SP = OFF_PM + NE;                  // srcp   [NE]
constexpr size_t OFF_EP = ((OFF_SP + NE) + 15) & ~(size_t)15;  // eattr_perm [NE*16]
constexpr size_t NEED_WORDS = OFF_EP + (size_t)NE * 16; // ~116 MB
// R7 post-mortem: every round R1-R7 ran at FETCH/dur = 1.15-1.35 TB/s -> the
// wall is random-gather bandwidth on the L2-miss path, invariant because the
// bucket-permuted eattr gather (1.6M x 64B random, 128B-granule => ~204MB)
// never changed. Fix: physically reorder eattr (+src) into bucket order with
// ONE pass of streaming reads + scattered WRITES (fire-and-forget), so k_edge
// reads eattr/src sequentially. Fallback to gather path if ws too small.

// ---------------- pass A: per-block bucket histogram (+ zero g) ----------------
__global__ __launch_bounds__(256) void k_hist(const int* __restrict__ ei,
                                              int* __restrict__ bh,
                                              float* __restrict__ g) {
  __shared__ int lh[NBKT];
  for (int i = threadIdx.x; i < NBKT; i += 256) lh[i] = 0;
  __syncthreads();
  const int* dstp = ei + NE;
  int s = blockIdx.x * CHUNK;
  for (int i = s + threadIdx.x; i < s + CHUNK; i += 256)
    atomicAdd(&lh[dstp[i] >> 6], 1);                    // LDS int atomic
  int gid = blockIdx.x * 256 + threadIdx.x;             // zero g: 12,500 float4
  if (gid < 12500) ((float4*)g)[gid] = make_float4(0.f, 0.f, 0.f, 0.f);
  __syncthreads();
  int* out = bh + (size_t)blockIdx.x * NBKT;            // block-major: coalesced
  for (int k = threadIdx.x; k < NBKT; k += 256) out[k] = lh[k];
}

// ---------------- pass B1: per-bucket totals (grid-parallel) ----------------
__global__ __launch_bounds__(256) void k_btot(const int* __restrict__ bh,
                                              int* __restrict__ starts) {
  int k = blockIdx.x * 256 + threadIdx.x;
  if (k >= NBKT) return;
  int tot = 0;
  for (int b = 0; b < NB; b += 4) {                     // coalesced: k-consecutive
    int a0 = bh[(size_t)(b    ) * NBKT + k];
    int a1 = bh[(size_t)(b + 1) * NBKT + k];
    int a2 = bh[(size_t)(b + 2) * NBKT + k];
    int a3 = bh[(size_t)(b + 3) * NBKT + k];
    tot += a0 + a1 + a2 + a3;
  }
  starts[k] = tot;
}

// ---------------- pass B2: exclusive scan of 1563 totals ----------------
__global__ __launch_bounds__(1024) void k_sscan(int* __restrict__ starts) {
  __shared__ int s0[1024], s1[1024];
  int t = threadIdx.x;
  int k0 = 2 * t, k1 = 2 * t + 1;
  int tot0 = (k0 < NBKT) ? starts[k0] : 0;
  int tot1 = (k1 < NBKT) ? starts[k1] : 0;
  int ssum = tot0 + tot1;
  int* cur = s0; int* nxt = s1;
  cur[t] = ssum;
  __syncthreads();
  for (int off = 1; off < 1024; off <<= 1) {            // Hillis-Steele inclusive
    int v = cur[t];
    if (t >= off) v += cur[t - off];
    nxt[t] = v;
    __syncthreads();
    int* tmp = cur; cur = nxt; nxt = tmp;
  }
  int excl = cur[t] - ssum;
  if (k0 < NBKT) starts[k0] = excl;
  if (k1 <= NBKT) starts[k1] = excl + tot0;             // t=781 writes starts[NBKT]=NE
}

// ---------------- pass B3: per-(block,bucket) bases (grid-parallel) ----------------
__global__ __launch_bounds__(256) void k_bases(int* __restrict__ bh,
                                               const int* __restrict__ starts) {
  int k = blockIdx.x * 256 + threadIdx.x;
  if (k >= NBKT) return;
  int run = starts[k];
  for (int b = 0; b < NB; ++b) {
    size_t idx = (size_t)b * NBKT + k;
    int v = bh[idx];
    bh[idx] = run;
    run += v;
  }
}

// ---------------- pass C: scatter edge ids (or inverse slots) ----------------
template <bool PRE>
__global__ __launch_bounds__(256) void k_scatter(const int* __restrict__ ei,
                                                 const int* __restrict__ bh,
                                                 int* __restrict__ pm) {
  __shared__ int base[NBKT];
  __shared__ int cnt[NBKT];
  const int* row = bh + (size_t)blockIdx.x * NBKT;
  for (int k = threadIdx.x; k < NBKT; k += 256) { base[k] = row[k]; cnt[k] = 0; }
  __syncthreads();
  const int* dstp = ei + NE;
  int s = blockIdx.x * CHUNK;
  for (int i = s + threadIdx.x; i < s + CHUNK; i += 256) {
    int d = dstp[i];
    int k = d >> 6;
    int r = atomicAdd(&cnt[k], 1);                      // LDS atomic
    int slot = base[k] + r;
    if (PRE) pm[i] = slot | ((d & 63) << 25);           // inv: coalesced write
    else     pm[slot] = i | ((d & 63) << 24);           // perm: scattered write
  }
}

// ---------------- pass C2: stream eattr -> bucket-ordered copy ----------------
// Streaming reads (fully coalesced: 4 lanes x float4 per edge), scattered
// 64B-aligned writes (4 lanes hit one 64B line). srcp[slot] = src | dl<<24.
__global__ __launch_bounds__(256) void k_reorder(const int* __restrict__ ei,
                                                 const float* __restrict__ eattr,
                                                 const int* __restrict__ inv,
                                                 float* __restrict__ ep_,
                                                 int* __restrict__ srcp) {
  int gid = blockIdx.x * 256 + threadIdx.x;
  int e = gid >> 2, part = gid & 3;
  if (e >= NE) return;
  int iv = inv[e];
  int slot = iv & 0x1FFFFFF;                            // 25 bits
  float4 v = ((const float4*)eattr)[(size_t)e * 4 + part];
  ((float4*)ep_)[(size_t)slot * 4 + part] = v;
  if (part == 0) srcp[slot] = ei[e] | ((iv >> 25) << 24);
}

// ---------------- pass D: edge MLP + fused node MLP + graph pooling ----------------
// Lane (ep,jp): ep = edge slot (6/wave), jp = output pair (10).
// PRE=true: eattr_perm + srcp are STREAMED by slot (no gather, no ei read);
// only nattr[src] remains random (6.4MB, L2-mostly). PRE=false: R7 gather path.
// Weights: 96 pinned regs (R6 lesson: LDS re-reads of invariants waste pipe).
// Cooperative staging (R6): feature bytes touched once, via per-wave LDS slab.
#define PK4(V, K0) \
  a0 = __builtin_elementwise_fma(v2f{(V).x, (V).x}, W[K0+0], a0); \
  a1 = __builtin_elementwise_fma(v2f{(V).y, (V).y}, W[K0+1], a1); \
  a2 = __builtin_elementwise_fma(v2f{(V).z, (V).z}, W[K0+2], a2); \
  a3 = __builtin_elementwise_fma(v2f{(V).w, (V).w}, W[K0+3], a3);

template <bool PRE>
__global__ __launch_bounds__(512, 1) void k_edge(
    const int* __restrict__ ei,
    const float* __restrict__ nattr,
    const float* __restrict__ eattr,        // PRE: eattr_perm ; else raw eattr
    const float* __restrict__ Wm,
    const float* __restrict__ bm,
    const int* __restrict__ batch,
    const float* __restrict__ W1,
    const float* __restrict__ b1,
    const int* __restrict__ pm,             // PRE: srcp ; else perm
    const int* __restrict__ starts,
    float* __restrict__ g) {
  __shared__ float xt[20 * 65];    // padded rows
  __shared__ float gb[64 * 10];    // graph partials for this bucket's span
  __shared__ float4 wt4[250];      // weight bounce: [jp][t] pairs for cols 2jp,2jp+1
  __shared__ float4 us4[64 * 5];   // dst rows, padded stride 5 (4 used)
  __shared__ float4 feat[8 * 54];  // per-wave staged e/n features, stride 9 (8 used)
  __shared__ int s_se[2];
  __shared__ int s_bmin;
  int tid = threadIdx.x;
  for (int i = tid; i < 20 * 65; i += 512) xt[i] = 0.f;
  for (int i = tid; i < 640; i += 512) gb[i] = 0.f;
  if (tid < 240) {
    int j = tid / 24, t = tid - j * 24, k = 2 * t;
    wt4[j * 25 + t] = make_float4(Wm[k * 20 + 2 * j],       Wm[k * 20 + 2 * j + 1],
                                  Wm[(k + 1) * 20 + 2 * j], Wm[(k + 1) * 20 + 2 * j + 1]);
  }
  int nbase = blockIdx.x * BKT;
  if (tid < 256) {                 // stage the block's 64 dst rows (once)
    int dl = tid >> 2, part = tid & 3;
    int row = min(nbase + dl, NN - 1);
    us4[dl * 5 + part] = ((const float4*)nattr)[(size_t)row * 4 + part];
  }
  if (tid < 2) s_se[tid] = starts[blockIdx.x + tid];
  if (tid == 0) s_bmin = batch[nbase];
  __syncthreads();
  int is = s_se[0], ie = s_se[1];

  int wave = tid >> 6;             // 0..7
  int lane = tid & 63;
  int ep = lane / 10;              // 0..6 (6 -> idle lane)
  int jp = lane - ep * 10;         // 0..9
  bool act = ep < 6;
  int epc = act ? ep : 0;

  v2f bj = {bm[2 * jp], bm[2 * jp + 1]};

  // resident weights: 96 VGPRs, loaded ONCE via LDS bounce, pinned.
  v2f W[48];
#pragma unroll
  for (int t = 0; t < 24; ++t) {
    float4 q = wt4[jp * 25 + t];
    W[2 * t]     = v2f{q.x, q.y};
    W[2 * t + 1] = v2f{q.z, q.w};
  }
#pragma unroll
  for (int k = 0; k < 48; ++k) asm volatile("" : "+v"(W[k]));

  // chunk-loader mapping: lane<48 stages one float4: edge ce=lane>>3, part=lane&7
  int ce = lane >> 3, cpart = lane & 7;
  bool ldr = lane < 48;
  int esrc = (ldr ? ce : 0) * 10;  // lane holding the slot-record of edge ce
  int fbase = wave * 54;

  int base = is + wave * 6;
  if (PRE) {
    // ---- streaming path: sp = srcp[slot] (src | dl<<24), eattr by direct addr ----
    int sp0 = 0, sp1 = 0;
    float4 st = make_float4(0.f, 0.f, 0.f, 0.f);
    if (base < ie) {
      sp0 = pm[min(base + epc, ie - 1)];
      sp1 = (base + 48 < ie) ? pm[min(base + 48 + epc, ie - 1)] : sp0;
      int ss = __shfl(sp0, esrc) & 0xFFFFFF;
      if (ldr) {
        st = (cpart < 4)
          ? ((const float4*)eattr)[(size_t)min(base + ce, ie - 1) * 4 + cpart]
          : ((const float4*)nattr)[(size_t)ss * 4 + (cpart - 4)];
      }
    }
    while (base < ie) {
      if (ldr) feat[fbase + ce * 9 + cpart] = st;        // publish iter-i stage
      int ss = __shfl(sp1, esrc) & 0xFFFFFF;             // next iter's src
      int sp2 = (base + 96 < ie) ? pm[min(base + 96 + epc, ie - 1)] : sp1;
      if (ldr) {                                         // stage iter i+1
        st = (cpart < 4)
          ? ((const float4*)eattr)[(size_t)min(base + 48 + ce, ie - 1) * 4 + cpart]
          : ((const float4*)nattr)[(size_t)ss * 4 + (cpart - 4)];
      }
      int dl = (sp0 >> 24) & 63;
      int frow = fbase + ep * 9;
      float4 e0 = feat[frow + 0], e1 = feat[frow + 1], e2 = feat[frow + 2], e3 = feat[frow + 3];
      float4 n0 = feat[frow + 4], n1 = feat[frow + 5], n2 = feat[frow + 6], n3 = feat[frow + 7];
      float4 u0 = us4[dl * 5 + 0], u1 = us4[dl * 5 + 1], u2 = us4[dl * 5 + 2], u3 = us4[dl * 5 + 3];

      v2f a0 = {0.f, 0.f}, a1 = {0.f, 0.f}, a2 = {0.f, 0.f}, a3 = {0.f, 0.f};
      PK4(n0, 0)  PK4(n1, 4)  PK4(n2, 8)  PK4(n3, 12)
      PK4(u0, 16) PK4(u1, 20) PK4(u2, 24) PK4(u3, 28)
      PK4(e0, 32) PK4(e1, 36) PK4(e2, 40) PK4(e3, 44)
      v2f r = ((a0 + a1) + (a2 + a3)) + bj;

      bool valid = act && (base + epc < ie);
      float m0 = fmaxf(r.x, 0.f);
      float m1 = fmaxf(r.y, 0.f);
      if (valid && m0 > 0.f) atomicAdd(&xt[(2 * jp) * 65 + dl], m0);
      if (valid && m1 > 0.f) atomicAdd(&xt[(2 * jp + 1) * 65 + dl], m1);

      base += 48; sp0 = sp1; sp1 = sp2;
    }
  } else {
    // ---- fallback gather path (exact R7 structure) ----
    int p0 = 0, p1 = 0, p2 = 0, svn = 0;
    float4 st = make_float4(0.f, 0.f, 0.f, 0.f);
    if (base < ie) {
      p0 = pm[min(base + epc, ie - 1)];
      p1 = (base + 48 < ie) ? pm[min(base + 48 + epc, ie - 1)] : p0;
      p2 = (base + 96 < ie) ? pm[min(base + 96 + epc, ie - 1)] : p1;
      int sv0 = ei[p0 & 0xFFFFFF];
      svn     = ei[p1 & 0xFFFFFF];
      int pp = __shfl(p0, esrc);
      int ss = __shfl(sv0, esrc);
      if (ldr) {
        st = (cpart < 4)
          ? ((const float4*)eattr)[(size_t)(pp & 0xFFFFFF) * 4 + cpart]
          : ((const float4*)nattr)[(size_t)ss * 4 + (cpart - 4)];
      }
    }
    while (base < ie) {
      if (ldr) feat[fbase + ce * 9 + cpart] = st;
      int pp = __shfl(p1, esrc);
      int ss = __shfl(svn, esrc);
      int p3 = (base + 144 < ie) ? pm[min(base + 144 + epc, ie - 1)] : p2;
      int svn2 = ei[p2 & 0xFFFFFF];
      if (ldr) {
        st = (cpart < 4)
          ? ((const float4*)eattr)[(size_t)(pp & 0xFFFFFF) * 4 + cpart]
          : ((const float4*)nattr)[(size_t)ss * 4 + (cpart - 4)];
      }
      int dl = (p0 >> 24) & 63;
      int frow = fbase + ep * 9;
      float4 e0 = feat[frow + 0], e1 = feat[frow + 1], e2 = feat[frow + 2], e3 = feat[frow + 3];
      float4 n0 = feat[frow + 4], n1 = feat[frow + 5], n2 = feat[frow + 6], n3 = feat[frow + 7];
      float4 u0 = us4[dl * 5 + 0], u1 = us4[dl * 5 + 1], u2 = us4[dl * 5 + 2], u3 = us4[dl * 5 + 3];

      v2f a0 = {0.f, 0.f}, a1 = {0.f, 0.f}, a2 = {0.f, 0.f}, a3 = {0.f, 0.f};
      PK4(n0, 0)  PK4(n1, 4)  PK4(n2, 8)  PK4(n3, 12)
      PK4(u0, 16) PK4(u1, 20) PK4(u2, 24) PK4(u3, 28)
      PK4(e0, 32) PK4(e1, 36) PK4(e2, 40) PK4(e3, 44)
      v2f r = ((a0 + a1) + (a2 + a3)) + bj;

      bool valid = act && (base + epc < ie);
      float m0 = fmaxf(r.x, 0.f);
      float m1 = fmaxf(r.y, 0.f);
      if (valid && m0 > 0.f) atomicAdd(&xt[(2 * jp) * 65 + dl], m0);
      if (valid && m1 > 0.f) atomicAdd(&xt[(2 * jp + 1) * 65 + dl], m1);

      base += 48; p0 = p1; p1 = p2; p2 = p3; svn = svn2;
    }
  }
  __syncthreads();

  // ---- fused node MLP (20 -> 10, relu) + graph pre-aggregation ----
  int nn = min(BKT, NN - nbase);
  int bmin = s_bmin;
  if (tid < 64 && tid < nn) {
    int node = tid;
    float xi[20];
#pragma unroll
    for (int j = 0; j < 20; ++j) xi[j] = xt[j * 65 + node];
    float acc[10];
#pragma unroll
    for (int j = 0; j < 10; ++j) acc[j] = b1[j];
#pragma unroll
    for (int k = 0; k < 20; ++k) {
      float fk = xi[k];
#pragma unroll
      for (int j = 0; j < 10; ++j) acc[j] = fmaf(fk, W1[k * 10 + j], acc[j]);
    }
    int bn = batch[nbase + node];
    int d = bn - bmin;                                  // >= 0 (batch sorted)
    if (d < 64) {
#pragma unroll
      for (int j = 0; j < 10; ++j) {
        float m = fmaxf(acc[j], 0.f);
        if (m > 0.f) atomicAdd(&gb[d * 10 + j], m);     // LDS
      }
    } else {                                            // rare large jump
#pragma unroll
      for (int j = 0; j < 10; ++j) {
        float m = fmaxf(acc[j], 0.f);
        if (m > 0.f) unsafeAtomicAdd(&g[(size_t)bn * 10 + j], m);
      }
    }
  }
  __syncthreads();
  int glim = min(640, NG * 10 - bmin * 10);
  float* gp = g + (size_t)bmin * 10;
  for (int idx = tid; idx < glim; idx += 512) {
    float v = gb[idx];
    if (v != 0.f) unsafeAtomicAdd(&gp[idx], v);         // ~40 sparse atomics/block
  }
}

// ---------------- graph MLP ----------------
__global__ __launch_bounds__(256) void k_graph(
    const float* __restrict__ g,
    const float* __restrict__ W2, const float* __restrict__ b2,
    const float* __restrict__ W3, const float* __restrict__ b3,
    float* __restrict__ out) {
  int i = blockIdx.x * 256 + threadIdx.x;
  if (i >= NG) return;
  float gi[10];
  const float2* pg = (const float2*)(g + (size_t)i * 10);
#pragma unroll
  for (int k = 0; k < 5; ++k) { float2 v = pg[k]; gi[2*k] = v.x; gi[2*k+1] = v.y; }
  float o = b3[0];
#pragma unroll
  for (int j = 0; j < 10; ++j) {
    float a = b2[j];
#pragma unroll
    for (int k = 0; k < 10; ++k) a = fmaf(gi[k], W2[k * 10 + j], a);
    o = fmaf(fmaxf(a, 0.f), W3[j], o);
  }
  out[i] = o;
}

extern "C" void kernel_launch(void* const* d_in, const int* in_sizes, int n_in,
                              void* d_out, int out_size, void* d_ws, size_t ws_size,
                              hipStream_t stream) {
  const int*   ei    = (const int*)  d_in[0];
  const float* nattr = (const float*)d_in[1];
  const float* eattr = (const float*)d_in[2];
  const int*   batch = (const int*)  d_in[3];
  const float* Wm    = (const float*)d_in[4];
  const float* bm    = (const float*)d_in[5];
  const float* W1    = (const float*)d_in[6];
  const float* b1    = (const float*)d_in[7];
  const float* W2    = (const float*)d_in[8];
  const float* b2    = (const float*)d_in[9];
  const float* W3    = (const float*)d_in[10];
  const float* b3    = (const float*)d_in[11];

  float* g      = (float*)d_ws + OFF_G;
  int*   bh     = (int*)d_ws + OFF_BH;
  int*   starts = (int*)d_ws + OFF_ST;
  int*   pm     = (int*)d_ws + OFF_PM;     // perm or inv
  int*   srcp   = (int*)d_ws + OFF_SP;
  float* ep_    = (float*)d_ws + OFF_EP;

  bool pre = ws_size >= NEED_WORDS * 4;

  constexpr int SCAN_BLKS = (NBKT + 255) / 256;   // 7

  k_hist   <<<NB, 256, 0, stream>>>(ei, bh, g);
  k_btot   <<<SCAN_BLKS, 256, 0, stream>>>(bh, starts);
  k_sscan  <<<1, 1024, 0, stream>>>(starts);
  k_bases  <<<SCAN_BLKS, 256, 0, stream>>>(bh, starts);
  if (pre) {
    k_scatter<true><<<NB, 256, 0, stream>>>(ei, bh, pm);
    k_reorder<<<(NE * 4 + 255) / 256, 256, 0, stream>>>(ei, eattr, pm, ep_, srcp);
    k_edge<true><<<NBKT, 512, 0, stream>>>(ei, nattr, ep_, Wm, bm, batch, W1, b1,
                                           srcp, starts, g);
  } else {
    k_scatter<false><<<NB, 256, 0, stream>>>(ei, bh, pm);
    k_edge<false><<<NBKT, 512, 0, stream>>>(ei, nattr, eattr, Wm, bm, batch, W1, b1,
                                            pm, starts, g);
  }
  k_graph  <<<(NG + 255) / 256, 256, 0, stream>>>(g, W2, b2, W3, b3, (float*)d_out);
}

// Round 9
// 382.712 us; speedup vs baseline: 1.1502x; 1.1502x over previous
//
#include <hip/hip_runtime.h>

constexpr int NN = 100000;   // nodes
constexpr int NE = 1600000;  // edges
constexpr int NG = 5000;     // graphs
constexpr int BKT = 64;      // dst-nodes per bucket
constexpr int NBKT = (NN + BKT - 1) / BKT;   // 1563
constexpr int NB = 128;      // hist/scatter blocks
constexpr int CHUNK = NE / NB;               // 12500 exact

typedef float v2f __attribute__((ext_vector_type(2)));

// ---- workspace layout (4B words) ----
constexpr size_t OFF_G  = 0;                            // g      [NG*10]
constexpr size_t OFF_BH = 50048;                        // bh     [NB][NBKT]
constexpr size_t OFF_ST = OFF_BH + (size_t)NB * NBKT;   // starts [NBKT+1]
constexpr size_t OFF_PM = OFF_ST + NBKT + 1;            // perm OR inv [NE]
constexpr size_t OFF_SP = OFF_PM + NE;                  // srcp   [NE]
constexpr size_t OFF_EP = ((OFF_SP + NE) + 15) & ~(size_t)15;  // eattr_perm [NE*16]
constexpr size_t NEED_WORDS = OFF_EP + (size_t)NE * 16; // ~116 MB (proven fits, R8)
// R8 post-mortem: FETCH halved (258->117MB) but dur 204->194.6 => NOT BW-bound.
// VALUBusy 23% @ 2 waves/SIMD == latency-bound signature (per-iter critical
// path ~3.6Kcyc, only ~400cyc VALU). 512-thread blocks QUANTIZE occupancy:
// 168 unified regs (72 arch + 96 AGPR pinned W) -> 1 block/CU -> 2 waves/SIMD.
// R9: 256-thread blocks + (256,3) => 3 waves/SIMD at the same 168 regs; and
// delete staging/shfl (R6 proved redundant same-addr lanes are coalescer-free)
// -> affine loads for eattr_perm/srcp, single dependent hop (nattr[src], L2).

// ---------------- pass A: per-block bucket histogram (+ zero g) ----------------
__global__ __launch_bounds__(256) void k_hist(const int* __restrict__ ei,
                                              int* __restrict__ bh,
                                              float* __restrict__ g) {
  __shared__ int lh[NBKT];
  for (int i = threadIdx.x; i < NBKT; i += 256) lh[i] = 0;
  __syncthreads();
  const int* dstp = ei + NE;
  int s = blockIdx.x * CHUNK;
  for (int i = s + threadIdx.x; i < s + CHUNK; i += 256)
    atomicAdd(&lh[dstp[i] >> 6], 1);                    // LDS int atomic
  int gid = blockIdx.x * 256 + threadIdx.x;             // zero g: 12,500 float4
  if (gid < 12500) ((float4*)g)[gid] = make_float4(0.f, 0.f, 0.f, 0.f);
  __syncthreads();
  int* out = bh + (size_t)blockIdx.x * NBKT;            // block-major: coalesced
  for (int k = threadIdx.x; k < NBKT; k += 256) out[k] = lh[k];
}

// ---------------- pass B1: per-bucket totals (grid-parallel) ----------------
__global__ __launch_bounds__(256) void k_btot(const int* __restrict__ bh,
                                              int* __restrict__ starts) {
  int k = blockIdx.x * 256 + threadIdx.x;
  if (k >= NBKT) return;
  int tot = 0;
  for (int b = 0; b < NB; b += 4) {                     // coalesced: k-consecutive
    int a0 = bh[(size_t)(b    ) * NBKT + k];
    int a1 = bh[(size_t)(b + 1) * NBKT + k];
    int a2 = bh[(size_t)(b + 2) * NBKT + k];
    int a3 = bh[(size_t)(b + 3) * NBKT + k];
    tot += a0 + a1 + a2 + a3;
  }
  starts[k] = tot;
}

// ---------------- pass B2: exclusive scan of 1563 totals ----------------
__global__ __launch_bounds__(1024) void k_sscan(int* __restrict__ starts) {
  __shared__ int s0[1024], s1[1024];
  int t = threadIdx.x;
  int k0 = 2 * t, k1 = 2 * t + 1;
  int tot0 = (k0 < NBKT) ? starts[k0] : 0;
  int tot1 = (k1 < NBKT) ? starts[k1] : 0;
  int ssum = tot0 + tot1;
  int* cur = s0; int* nxt = s1;
  cur[t] = ssum;
  __syncthreads();
  for (int off = 1; off < 1024; off <<= 1) {            // Hillis-Steele inclusive
    int v = cur[t];
    if (t >= off) v += cur[t - off];
    nxt[t] = v;
    __syncthreads();
    int* tmp = cur; cur = nxt; nxt = tmp;
  }
  int excl = cur[t] - ssum;
  if (k0 < NBKT) starts[k0] = excl;
  if (k1 <= NBKT) starts[k1] = excl + tot0;             // t=781 writes starts[NBKT]=NE
}

// ---------------- pass B3: per-(block,bucket) bases (grid-parallel) ----------------
__global__ __launch_bounds__(256) void k_bases(int* __restrict__ bh,
                                               const int* __restrict__ starts) {
  int k = blockIdx.x * 256 + threadIdx.x;
  if (k >= NBKT) return;
  int run = starts[k];
  for (int b = 0; b < NB; ++b) {
    size_t idx = (size_t)b * NBKT + k;
    int v = bh[idx];
    bh[idx] = run;
    run += v;
  }
}

// ---------------- pass C: scatter edge ids (or inverse slots) ----------------
template <bool PRE>
__global__ __launch_bounds__(256) void k_scatter(const int* __restrict__ ei,
                                                 const int* __restrict__ bh,
                                                 int* __restrict__ pm) {
  __shared__ int base[NBKT];
  __shared__ int cnt[NBKT];
  const int* row = bh + (size_t)blockIdx.x * NBKT;
  for (int k = threadIdx.x; k < NBKT; k += 256) { base[k] = row[k]; cnt[k] = 0; }
  __syncthreads();
  const int* dstp = ei + NE;
  int s = blockIdx.x * CHUNK;
  for (int i = s + threadIdx.x; i < s + CHUNK; i += 256) {
    int d = dstp[i];
    int k = d >> 6;
    int r = atomicAdd(&cnt[k], 1);                      // LDS atomic
    int slot = base[k] + r;
    if (PRE) pm[i] = slot | ((d & 63) << 25);           // inv: coalesced write
    else     pm[slot] = i | ((d & 63) << 24);           // perm: scattered write
  }
}

// ---------------- pass C2: stream eattr -> bucket-ordered copy ----------------
// Streaming reads (fully coalesced), scattered 64B-aligned writes.
// srcp[slot] = src | dl<<24.
__global__ __launch_bounds__(256) void k_reorder(const int* __restrict__ ei,
                                                 const float* __restrict__ eattr,
                                                 const int* __restrict__ inv,
                                                 float* __restrict__ ep_,
                                                 int* __restrict__ srcp) {
  int gid = blockIdx.x * 256 + threadIdx.x;
  int e = gid >> 2, part = gid & 3;
  if (e >= NE) return;
  int iv = inv[e];
  int slot = iv & 0x1FFFFFF;                            // 25 bits
  float4 v = ((const float4*)eattr)[(size_t)e * 4 + part];
  ((float4*)ep_)[(size_t)slot * 4 + part] = v;
  if (part == 0) srcp[slot] = ei[e] | ((iv >> 25) << 24);
}

// ---------------- pass D: edge MLP + fused node MLP + graph pooling ----------------
// Lane (ep,jp): ep = edge slot (6/wave), jp = output pair (10). 4 waves/block.
// PRE: all addresses affine (eattr_perm, srcp streaming) except the single
// dependent hop nattr[src] (6.4MB, L2-mostly). Direct per-lane loads —
// same-address lanes merge in the coalescer (R6 lesson: staging bought nothing
// and cost LDS/shfl ops). Weights: 96 pinned regs (R7). In-loop LDS = 4 us
// reads + 2 atomics only.
#define PK4(V, K0) \
  a0 = __builtin_elementwise_fma(v2f{(V).x, (V).x}, W[K0+0], a0); \
  a1 = __builtin_elementwise_fma(v2f{(V).y, (V).y}, W[K0+1], a1); \
  a2 = __builtin_elementwise_fma(v2f{(V).z, (V).z}, W[K0+2], a2); \
  a3 = __builtin_elementwise_fma(v2f{(V).w, (V).w}, W[K0+3], a3);

template <bool PRE>
__global__ __launch_bounds__(256, 3) void k_edge(
    const int* __restrict__ ei,
    const float* __restrict__ nattr,
    const float* __restrict__ eattr,        // PRE: eattr_perm ; else raw eattr
    const float* __restrict__ Wm,
    const float* __restrict__ bm,
    const int* __restrict__ batch,
    const float* __restrict__ W1,
    const float* __restrict__ b1,
    const int* __restrict__ pm,             // PRE: srcp ; else perm
    const int* __restrict__ starts,
    float* __restrict__ g) {
  __shared__ float xt[20 * 65];    // padded rows
  __shared__ float gb[64 * 10];    // graph partials for this bucket's span
  __shared__ float4 wt4[250];      // weight bounce: [jp][t] pairs for cols 2jp,2jp+1
  __shared__ float4 us4[64 * 5];   // dst rows, padded stride 5 (4 used)
  __shared__ int s_se[2];
  __shared__ int s_bmin;
  int tid = threadIdx.x;
  for (int i = tid; i < 20 * 65; i += 256) xt[i] = 0.f;
  for (int i = tid; i < 640; i += 256) gb[i] = 0.f;
  if (tid < 240) {
    int j = tid / 24, t = tid - j * 24, k = 2 * t;
    wt4[j * 25 + t] = make_float4(Wm[k * 20 + 2 * j],       Wm[k * 20 + 2 * j + 1],
                                  Wm[(k + 1) * 20 + 2 * j], Wm[(k + 1) * 20 + 2 * j + 1]);
  }
  int nbase = blockIdx.x * BKT;
  {                                // stage the block's 64 dst rows (once)
    int dl = tid >> 2, part = tid & 3;
    int row = min(nbase + dl, NN - 1);
    us4[dl * 5 + part] = ((const float4*)nattr)[(size_t)row * 4 + part];
  }
  if (tid < 2) s_se[tid] = starts[blockIdx.x + tid];
  if (tid == 0) s_bmin = batch[nbase];
  __syncthreads();
  int is = s_se[0], ie = s_se[1];

  int wave = tid >> 6;             // 0..3
  int lane = tid & 63;
  int ep = lane / 10;              // 0..6 (6 -> idle lane)
  int jp = lane - ep * 10;         // 0..9
  bool act = ep < 6;
  int epc = act ? ep : 0;

  v2f bj = {bm[2 * jp], bm[2 * jp + 1]};

  // resident weights: 96 VGPRs, loaded ONCE via LDS bounce, pinned.
  v2f W[48];
#pragma unroll
  for (int t = 0; t < 24; ++t) {
    float4 q = wt4[jp * 25 + t];
    W[2 * t]     = v2f{q.x, q.y};
    W[2 * t + 1] = v2f{q.z, q.w};
  }
#pragma unroll
  for (int k = 0; k < 48; ++k) asm volatile("" : "+v"(W[k]));

  // 4 waves x 6 edges = stride 24. pm chain 2-deep (ints only); for the
  // gather fallback, src (ei) is 1-deep.
  int base = is + wave * 6;
  int sp0 = 0, sp1 = 0, sp2 = 0, sv0 = 0;
  if (base < ie) {
    sp0 = pm[min(base + epc, ie - 1)];
    sp1 = (base + 24 < ie) ? pm[min(base + 24 + epc, ie - 1)] : sp0;
    sp2 = (base + 48 < ie) ? pm[min(base + 48 + epc, ie - 1)] : sp1;
    if (!PRE) sv0 = ei[sp0 & 0xFFFFFF];
  }
  while (base < ie) {
    int sp3 = (base + 72 < ie) ? pm[min(base + 72 + epc, ie - 1)] : sp2;
    int svN = 0;
    if (!PRE) svN = (base + 24 < ie) ? ei[sp1 & 0xFFFFFF] : sv0;

    // feature loads: eattr affine (PRE) or gathered (fallback); nattr[src]
    // single dependent hop (L2-hot 6.4MB table). Redundant jp-lanes merge.
    size_t eidx = PRE ? (size_t)min(base + epc, ie - 1)
                      : (size_t)(sp0 & 0xFFFFFF);
    int src = PRE ? (sp0 & 0xFFFFFF) : sv0;
    const float4* pe = (const float4*)eattr + eidx * 4;
    const float4* ps = (const float4*)nattr + (size_t)src * 4;
    float4 e0 = pe[0], e1 = pe[1], e2 = pe[2], e3 = pe[3];
    float4 n0 = ps[0], n1 = ps[1], n2 = ps[2], n3 = ps[3];
    int dl = (sp0 >> 24) & 63;
    float4 u0 = us4[dl * 5 + 0], u1 = us4[dl * 5 + 1];
    float4 u2 = us4[dl * 5 + 2], u3 = us4[dl * 5 + 3];

    v2f a0 = {0.f, 0.f}, a1 = {0.f, 0.f}, a2 = {0.f, 0.f}, a3 = {0.f, 0.f};
    PK4(n0, 0)  PK4(n1, 4)  PK4(n2, 8)  PK4(n3, 12)     // src feats  (k 0..15)
    PK4(u0, 16) PK4(u1, 20) PK4(u2, 24) PK4(u3, 28)     // dst feats  (k 16..31)
    PK4(e0, 32) PK4(e1, 36) PK4(e2, 40) PK4(e3, 44)     // edge feats (k 32..47)
    v2f r = ((a0 + a1) + (a2 + a3)) + bj;

    bool valid = act && (base + epc < ie);
    float m0 = fmaxf(r.x, 0.f);
    float m1 = fmaxf(r.y, 0.f);
    if (valid && m0 > 0.f) atomicAdd(&xt[(2 * jp) * 65 + dl], m0);     // LDS
    if (valid && m1 > 0.f) atomicAdd(&xt[(2 * jp + 1) * 65 + dl], m1);

    base += 24; sp0 = sp1; sp1 = sp2; sp2 = sp3; sv0 = svN;
  }
  __syncthreads();

  // ---- fused node MLP (20 -> 10, relu) + graph pre-aggregation ----
  int nn = min(BKT, NN - nbase);
  int bmin = s_bmin;
  if (tid < 64 && tid < nn) {
    int node = tid;
    float xi[20];
#pragma unroll
    for (int j = 0; j < 20; ++j) xi[j] = xt[j * 65 + node];
    float acc[10];
#pragma unroll
    for (int j = 0; j < 10; ++j) acc[j] = b1[j];
#pragma unroll
    for (int k = 0; k < 20; ++k) {
      float fk = xi[k];
#pragma unroll
      for (int j = 0; j < 10; ++j) acc[j] = fmaf(fk, W1[k * 10 + j], acc[j]);
    }
    int bn = batch[nbase + node];
    int d = bn - bmin;                                  // >= 0 (batch sorted)
    if (d < 64) {
#pragma unroll
      for (int j = 0; j < 10; ++j) {
        float m = fmaxf(acc[j], 0.f);
        if (m > 0.f) atomicAdd(&gb[d * 10 + j], m);     // LDS
      }
    } else {                                            // rare large jump
#pragma unroll
      for (int j = 0; j < 10; ++j) {
        float m = fmaxf(acc[j], 0.f);
        if (m > 0.f) unsafeAtomicAdd(&g[(size_t)bn * 10 + j], m);
      }
    }
  }
  __syncthreads();
  int glim = min(640, NG * 10 - bmin * 10);
  float* gp = g + (size_t)bmin * 10;
  for (int idx = tid; idx < glim; idx += 256) {
    float v = gb[idx];
    if (v != 0.f) unsafeAtomicAdd(&gp[idx], v);         // ~40 sparse atomics/block
  }
}

// ---------------- graph MLP ----------------
__global__ __launch_bounds__(256) void k_graph(
    const float* __restrict__ g,
    const float* __restrict__ W2, const float* __restrict__ b2,
    const float* __restrict__ W3, const float* __restrict__ b3,
    float* __restrict__ out) {
  int i = blockIdx.x * 256 + threadIdx.x;
  if (i >= NG) return;
  float gi[10];
  const float2* pg = (const float2*)(g + (size_t)i * 10);
#pragma unroll
  for (int k = 0; k < 5; ++k) { float2 v = pg[k]; gi[2*k] = v.x; gi[2*k+1] = v.y; }
  float o = b3[0];
#pragma unroll
  for (int j = 0; j < 10; ++j) {
    float a = b2[j];
#pragma unroll
    for (int k = 0; k < 10; ++k) a = fmaf(gi[k], W2[k * 10 + j], a);
    o = fmaf(fmaxf(a, 0.f), W3[j], o);
  }
  out[i] = o;
}

extern "C" void kernel_launch(void* const* d_in, const int* in_sizes, int n_in,
                              void* d_out, int out_size, void* d_ws, size_t ws_size,
                              hipStream_t stream) {
  const int*   ei    = (const int*)  d_in[0];
  const float* nattr = (const float*)d_in[1];
  const float* eattr = (const float*)d_in[2];
  const int*   batch = (const int*)  d_in[3];
  const float* Wm    = (const float*)d_in[4];
  const float* bm    = (const float*)d_in[5];
  const float* W1    = (const float*)d_in[6];
  const float* b1    = (const float*)d_in[7];
  const float* W2    = (const float*)d_in[8];
  const float* b2    = (const float*)d_in[9];
  const float* W3    = (const float*)d_in[10];
  const float* b3    = (const float*)d_in[11];

  float* g      = (float*)d_ws + OFF_G;
  int*   bh     = (int*)d_ws + OFF_BH;
  int*   starts = (int*)d_ws + OFF_ST;
  int*   pm     = (int*)d_ws + OFF_PM;     // perm or inv
  int*   srcp   = (int*)d_ws + OFF_SP;
  float* ep_    = (float*)d_ws + OFF_EP;

  bool pre = ws_size >= NEED_WORDS * 4;

  constexpr int SCAN_BLKS = (NBKT + 255) / 256;   // 7

  k_hist   <<<NB, 256, 0, stream>>>(ei, bh, g);
  k_btot   <<<SCAN_BLKS, 256, 0, stream>>>(bh, starts);
  k_sscan  <<<1, 1024, 0, stream>>>(starts);
  k_bases  <<<SCAN_BLKS, 256, 0, stream>>>(bh, starts);
  if (pre) {
    k_scatter<true><<<NB, 256, 0, stream>>>(ei, bh, pm);
    k_reorder<<<(NE * 4 + 255) / 256, 256, 0, stream>>>(ei, eattr, pm, ep_, srcp);
    k_edge<true><<<NBKT, 256, 0, stream>>>(ei, nattr, ep_, Wm, bm, batch, W1, b1,
                                           srcp, starts, g);
  } else {
    k_scatter<false><<<NB, 256, 0, stream>>>(ei, bh, pm);
    k_edge<false><<<NBKT, 256, 0, stream>>>(ei, nattr, eattr, Wm, bm, batch, W1, b1,
                                            pm, starts, g);
  }
  k_graph  <<<(NG + 255) / 256, 256, 0, stream>>>(g, W2, b2, W3, b3, (float*)d_out);
}